// Round 8
// baseline (97.681 us; speedup 1.0000x reference)
//
#include <hip/hip_runtime.h>
#include <hip/hip_bf16.h>

#define BSZ  131072
#define DIM  256
#define BM   32
#define NT   512            // 8 waves; wave w owns output cols [w*32, w*32+32)
#define GRID (BSZ / BM)     // 4096

typedef __attribute__((ext_vector_type(8))) short bf16x8;
typedef __attribute__((ext_vector_type(4))) float f32x4;
typedef __attribute__((ext_vector_type(2))) unsigned int u32x2;
typedef __attribute__((ext_vector_type(4))) unsigned short u16x4;

// LDS: ONE z tile (32 rows x 256 k, bf16). Row = 512B + 16B pad = 528B.
#define ZSTRIDE 528
// total 32*528 = 16896 B -> LDS never the occupancy limit

__device__ __forceinline__ unsigned short f2bf(float f) {
  unsigned u = __builtin_bit_cast(unsigned, f);
  return (unsigned short)((u + 0x7FFFu + ((u >> 16) & 1u)) >> 16);
}
__device__ __forceinline__ unsigned cvt_pk(float lo, float hi) {
  unsigned r;
  asm("v_cvt_pk_bf16_f32 %0, %1, %2" : "=v"(r) : "v"(lo), "v"(hi));
  return r;
}

// ---------------- prep: f32 W -> bf16 wT, K-major: wT[kb][j][kk] ----------------
__global__ void prep_kernel(const float* __restrict__ Wmu, const float* __restrict__ Wsd,
                            unsigned short* __restrict__ wm, unsigned short* __restrict__ wsd) {
  const int tg = blockIdx.x * 256 + threadIdx.x;   // 16384 threads
  const int j  = tg >> 6, kq = tg & 63;            // row j, k-quad (k0 = kq*4)
  const int dst = ((kq >> 3) << 13) + (j << 5) + ((kq & 7) << 2);
  f32x4 a = *(const f32x4*)(Wmu + j * 256 + kq * 4);
  f32x4 b = *(const f32x4*)(Wsd + j * 256 + kq * 4);
  u16x4 pa, pb;
#pragma unroll
  for (int e = 0; e < 4; ++e) { pa[e] = f2bf(a[e]); pb[e] = f2bf(b[e]); }
  *(u16x4*)(wm + dst)  = pa;
  *(u16x4*)(wsd + dst) = pb;
}

// ---------------- main fused kernel: small tile, 3 blocks/CU ----------------
__global__ __launch_bounds__(NT, 6)
void main_kernel(const float* __restrict__ z,
                 const unsigned short* __restrict__ wm,
                 const unsigned short* __restrict__ wsd,
                 const float* __restrict__ bmu,
                 const float* __restrict__ bsd,
                 float* __restrict__ out,
                 float* __restrict__ partials) {
  __shared__ unsigned char smem[BM * ZSTRIDE];   // 16896 B
  __shared__ float redbuf[8];
  const int t = threadIdx.x, lane = t & 63, w = t >> 6;
  const int bm = blockIdx.x;

  // ---- stage z tile: 4 x f32x4 per thread, coalesced ----
  const int zrow = t >> 4, c16 = t & 15;
  const float* zsrc = z + (size_t)(bm * BM + zrow) * DIM + c16 * 4;
  const int zw = zrow * ZSTRIDE + c16 * 8;   // + it*128

  f32x4 zv[4];
#pragma unroll
  for (int it = 0; it < 4; ++it) zv[it] = *(const f32x4*)(zsrc + it * 64);
#pragma unroll
  for (int it = 0; it < 4; ++it) {
    u32x2 p;
    p[0] = cvt_pk(zv[it][0], zv[it][1]);
    p[1] = cvt_pk(zv[it][2], zv[it][3]);
    *(u32x2*)(smem + zw + it * 128) = p;
  }
  __syncthreads();   // only block-wide barrier before epilogue

  // ---- W fragment sources: direct global (L2-resident), coalesced in K-major wT ----
  // elem = kb*8192 + (w*32 + mi*16 + (lane&15))*32 + (lane>>4)*8
  const int wlo = (lane & 15) * 32 + (lane >> 4) * 8;
  const unsigned short* wmb = wm  + w * 1024 + wlo;   // + mi*512 + kb*8192
  const unsigned short* wsb = wsd + w * 1024 + wlo;

  // z fragment read offset: row nj*16+(lane&15), unit lane>>4
  const int zro = (lane & 15) * ZSTRIDE + (lane >> 4) * 16;   // + nj*16*ZSTRIDE + kb*64

  f32x4 accm[2][2], accl[2][2];   // [mi][nj]
#pragma unroll
  for (int mi = 0; mi < 2; ++mi)
#pragma unroll
    for (int nj = 0; nj < 2; ++nj) { accm[mi][nj] = (f32x4)0.0f; accl[mi][nj] = (f32x4)0.0f; }

  // ---- K loop: 8 steps, no barriers; compiler schedules loads ahead within budget ----
#pragma unroll
  for (int kb = 0; kb < 8; ++kb) {
    const int ko = kb * 8192;
    bf16x8 wfm[2], wfs[2], zf[2];
    wfm[0] = *(const bf16x8*)(wmb + ko);
    wfm[1] = *(const bf16x8*)(wmb + ko + 512);
    wfs[0] = *(const bf16x8*)(wsb + ko);
    wfs[1] = *(const bf16x8*)(wsb + ko + 512);
#pragma unroll
    for (int nj = 0; nj < 2; ++nj)
      zf[nj] = *(const bf16x8*)(smem + kb * 64 + nj * 16 * ZSTRIDE + zro);

#pragma unroll
    for (int mi = 0; mi < 2; ++mi)
#pragma unroll
      for (int nj = 0; nj < 2; ++nj) {
        accm[mi][nj] = __builtin_amdgcn_mfma_f32_16x16x32_bf16(wfm[mi], zf[nj], accm[mi][nj], 0, 0, 0);
        accl[mi][nj] = __builtin_amdgcn_mfma_f32_16x16x32_bf16(wfs[mi], zf[nj], accl[mi][nj], 0, 0, 0);
      }
  }

  // ---- epilogue: bias + relu + KL + vectorized f32x4 stores ----
  float klp = 0.0f;
#pragma unroll
  for (int mi = 0; mi < 2; ++mi) {
    const int colb = w * 32 + mi * 16 + ((lane >> 4) << 2);
    const f32x4 b4m = *(const f32x4*)(bmu + colb);
    const f32x4 b4s = *(const f32x4*)(bsd + colb);
#pragma unroll
    for (int nj = 0; nj < 2; ++nj) {
      const size_t row = (size_t)(bm * BM + nj * 16 + (lane & 15));
      f32x4 mu4;
#pragma unroll
      for (int r = 0; r < 4; ++r) {
        float mu = fmaxf(accm[mi][nj][r] + b4m[r], 0.0f);
        float ls = fmaxf(accl[mi][nj][r] + b4s[r], 0.0f);
        float iv = __expf(-2.0f * ls);
        klp += fmaf(mu * mu, iv, iv) + 2.0f * ls;   // (1+mu^2)*iv + 2*ls; -1 folded below
        mu4[r] = mu;
      }
      *(f32x4*)(out + row * DIM + colb) = mu4;
    }
  }
  klp = 0.5f * (klp - 16.0f);   // 16 elements per lane

#pragma unroll
  for (int off = 32; off; off >>= 1) klp += __shfl_down(klp, off);
  if (lane == 0) redbuf[w] = klp;
  __syncthreads();
  if (t == 0) {
    float s = 0.0f;
#pragma unroll
    for (int i = 0; i < 8; ++i) s += redbuf[i];
    partials[bm] = s;
  }
}

// ---------------- finalize ----------------
__global__ void fin_kernel(const float* __restrict__ partials, float* __restrict__ out) {
  __shared__ double red[256];
  double s = 0.0;
  for (int i = threadIdx.x; i < GRID; i += 256) s += (double)partials[i];
  red[threadIdx.x] = s;
  __syncthreads();
  for (int st = 128; st > 0; st >>= 1) {
    if ((int)threadIdx.x < st) red[threadIdx.x] += red[threadIdx.x + st];
    __syncthreads();
  }
  if (threadIdx.x == 0) out[(size_t)BSZ * DIM] = (float)(red[0] / (double)BSZ);
}

// ---------------- launch ----------------
// ws: [0,16384) float partials[4096]; [16384,+128K) wT_mu; [147456,+128K) wT_sd.
// Total 278528 B (same as R1's proven requirement).
extern "C" void kernel_launch(void* const* d_in, const int* in_sizes, int n_in,
                              void* d_out, int out_size, void* d_ws, size_t ws_size,
                              hipStream_t stream) {
  const float* z   = (const float*)d_in[0];
  const float* Wmu = (const float*)d_in[1];
  const float* bmu = (const float*)d_in[2];
  const float* Wsd = (const float*)d_in[3];
  const float* bsd = (const float*)d_in[4];
  float* out = (float*)d_out;

  float* partials     = (float*)d_ws;
  unsigned short* wm  = (unsigned short*)((char*)d_ws + 16384);
  unsigned short* wsd = wm + DIM * DIM;

  prep_kernel<<<64, 256, 0, stream>>>(Wmu, Wsd, wm, wsd);
  main_kernel<<<GRID, NT, 0, stream>>>(z, wm, wsd, bmu, bsd, out, partials);
  fin_kernel<<<1, 256, 0, stream>>>(partials, out);
}

// Round 9
// 59.215 us; speedup vs baseline: 1.6496x; 1.6496x over previous
//
#include <hip/hip_runtime.h>
#include <hip/hip_bf16.h>

#define BSZ  131072
#define DIM  256
#define ROWS 32                    // rows per tile
#define NT   1024                  // 16 waves; wave w owns output cols [w*16, w*16+16)
#define NBLK 256                   // persistent: 1 block/CU
#define TPB  (BSZ / ROWS / NBLK)   // 16 tiles per block

typedef __attribute__((ext_vector_type(8))) short bf16x8;
typedef __attribute__((ext_vector_type(4))) float f32x4;
typedef __attribute__((ext_vector_type(4))) unsigned int u32x4;
typedef __attribute__((ext_vector_type(4))) unsigned short u16x4;

// LDS map:
//  zbuf[2] : [32 rows][256 bf16 + pad] stride 528  -> 2 x 16896
//  obuf    : [32 rows][256 f32 + pad]  stride 1040 -> 33280  @ 33792
// total 67072
#define ZSTR  528
#define OSTR  1040
#define OBASE 33792

__device__ __forceinline__ unsigned short f2bf(float f) {
  unsigned u = __builtin_bit_cast(unsigned, f);
  return (unsigned short)((u + 0x7FFFu + ((u >> 16) & 1u)) >> 16);
}
__device__ __forceinline__ unsigned cvt_pk(float lo, float hi) {
  unsigned r;
  asm("v_cvt_pk_bf16_f32 %0, %1, %2" : "=v"(r) : "v"(lo), "v"(hi));
  return r;
}

// ---------------- prep: f32 W -> bf16 wT, K-major: wT[kb][j][kk] ----------------
__global__ void prep_kernel(const float* __restrict__ Wmu, const float* __restrict__ Wsd,
                            unsigned short* __restrict__ wm, unsigned short* __restrict__ wsd) {
  const int tg = blockIdx.x * 256 + threadIdx.x;   // 16384 threads
  const int j  = tg >> 6, kq = tg & 63;            // row j, k-quad (k0 = kq*4)
  const int dst = ((kq >> 3) << 13) + (j << 5) + ((kq & 7) << 2);
  f32x4 a = *(const f32x4*)(Wmu + j * 256 + kq * 4);
  f32x4 b = *(const f32x4*)(Wsd + j * 256 + kq * 4);
  u16x4 pa, pb;
#pragma unroll
  for (int e = 0; e < 4; ++e) { pa[e] = f2bf(a[e]); pb[e] = f2bf(b[e]); }
  *(u16x4*)(wm + dst)  = pa;
  *(u16x4*)(wsd + dst) = pb;
}

// ---------------- main: persistent, W in registers, streaming z/out ----------------
__global__ __launch_bounds__(NT, 4)
void main_kernel(const float* __restrict__ z,
                 const unsigned short* __restrict__ wm,
                 const unsigned short* __restrict__ wsd,
                 const float* __restrict__ bmu,
                 const float* __restrict__ bsd,
                 float* __restrict__ out,
                 float* __restrict__ partials) {
  __shared__ unsigned char smem[67072];
  __shared__ float redbuf[16];
  const int t = threadIdx.x, lane = t & 63, w = t >> 6;   // w 0..15
  const int bid = blockIdx.x;

  // ---- W fragments, loaded ONCE into registers (wave w -> cols [w*16, w*16+16)) ----
  const int woff = (w * 16 + (lane & 15)) * 32 + (lane >> 4) * 8;
  bf16x8 wfm[8], wfs[8];
#pragma unroll
  for (int kb = 0; kb < 8; ++kb) {
    wfm[kb] = *(const bf16x8*)(wm  + (kb << 13) + woff);
    wfs[kb] = *(const bf16x8*)(wsd + (kb << 13) + woff);
  }
  const int colb = w * 16 + ((lane >> 4) << 2);
  const f32x4 b4m = *(const f32x4*)(bmu + colb);
  const f32x4 b4s = *(const f32x4*)(bsd + colb);

  // ---- per-thread addressing ----
  const int zrow = t >> 5, zc = t & 31;                       // stage: 8 f32 per thread
  const int zwofs = zrow * ZSTR + zc * 16;                    // ds_write_b128 dest
  const int zro   = (lane & 15) * ZSTR + (lane >> 4) * 16;    // + nj*16*ZSTR + kb*64
  const int ow    = (lane & 15) * OSTR + colb * 4;            // + nj*16*OSTR

  const size_t TSTEP = (size_t)NBLK * ROWS * DIM;             // elems between my tiles
  const float* zp = z + (size_t)(bid * ROWS + zrow) * DIM + zc * 8;
  float* op = out + (size_t)(bid * ROWS) * DIM;

  float klp = 0.0f;
  f32x4 pza, pzb;

  // ---- prologue: stage z(0) into buf0; prefetch z(1) into regs ----
  {
    f32x4 a = *(const f32x4*)zp;
    f32x4 b = *(const f32x4*)(zp + 4);
    u32x4 p;
    p[0] = cvt_pk(a[0], a[1]); p[1] = cvt_pk(a[2], a[3]);
    p[2] = cvt_pk(b[0], b[1]); p[3] = cvt_pk(b[2], b[3]);
    *(u32x4*)(smem + zwofs) = p;
  }
  pza = *(const f32x4*)(zp + TSTEP);
  pzb = *(const f32x4*)(zp + TSTEP + 4);
  asm volatile("s_waitcnt lgkmcnt(0)" ::: "memory");
  __builtin_amdgcn_sched_barrier(0);
  __builtin_amdgcn_s_barrier();

  // ---- tile loop: 16 tiles, pipelined; raw barriers, never drain vmcnt ----
#pragma unroll 1
  for (int i = 0; i < TPB; ++i) {
    const unsigned char* zb = smem + ((i & 1) ? 16896 : 0);

    f32x4 am[2], al[2];
    am[0] = (f32x4)0.0f; am[1] = (f32x4)0.0f;
    al[0] = (f32x4)0.0f; al[1] = (f32x4)0.0f;

#pragma unroll
    for (int kb = 0; kb < 8; ++kb)
#pragma unroll
      for (int nj = 0; nj < 2; ++nj) {
        const bf16x8 zf = *(const bf16x8*)(zb + nj * 16 * ZSTR + kb * 64 + zro);
        am[nj] = __builtin_amdgcn_mfma_f32_16x16x32_bf16(wfm[kb], zf, am[nj], 0, 0, 0);
        al[nj] = __builtin_amdgcn_mfma_f32_16x16x32_bf16(wfs[kb], zf, al[nj], 0, 0, 0);
      }

    // epilogue -> obuf (LDS), KL accumulate
#pragma unroll
    for (int nj = 0; nj < 2; ++nj) {
      f32x4 mu4;
#pragma unroll
      for (int r = 0; r < 4; ++r) {
        float mu = fmaxf(am[nj][r] + b4m[r], 0.0f);
        float ls = fmaxf(al[nj][r] + b4s[r], 0.0f);
        float iv = __expf(-2.0f * ls);
        klp += fmaf(mu * mu, iv, iv) + 2.0f * ls;   // (1+mu^2)*iv + 2*ls; -1 folded at end
        mu4[r] = mu;
      }
      *(f32x4*)(smem + OBASE + nj * 16 * OSTR + ow) = mu4;
    }
    asm volatile("s_waitcnt lgkmcnt(0)" ::: "memory");
    __builtin_amdgcn_sched_barrier(0);
    __builtin_amdgcn_s_barrier();          // B1: obuf complete; z(i) reads retired

    // coalesced nontemporal stores: wave stores rows 2w, 2w+1 (1KB contiguous each)
#pragma unroll
    for (int rr = 0; rr < 2; ++rr) {
      const int row = w * 2 + rr;
      const f32x4 v = *(const f32x4*)(smem + OBASE + row * OSTR + lane * 16);
      __builtin_nontemporal_store(v, (f32x4*)(op + (size_t)i * TSTEP + row * DIM + lane * 4));
    }

    // stage z(i+1) (regs -> LDS other buffer), then prefetch z(i+2)
    if (i < TPB - 1) {
      u32x4 p;
      p[0] = cvt_pk(pza[0], pza[1]); p[1] = cvt_pk(pza[2], pza[3]);
      p[2] = cvt_pk(pzb[0], pzb[1]); p[3] = cvt_pk(pzb[2], pzb[3]);
      *(u32x4*)(smem + (((i + 1) & 1) ? 16896 : 0) + zwofs) = p;
    }
    if (i < TPB - 2) {
      pza = *(const f32x4*)(zp + (size_t)(i + 2) * TSTEP);
      pzb = *(const f32x4*)(zp + (size_t)(i + 2) * TSTEP + 4);
    }
    asm volatile("s_waitcnt lgkmcnt(0)" ::: "memory");
    __builtin_amdgcn_sched_barrier(0);
    __builtin_amdgcn_s_barrier();          // B2: z(i+1) staged; obuf reads retired
  }

  // ---- KL reduction ----
  klp = 0.5f * (klp - (float)(TPB * 8));   // 128 elems per lane, each owes -1
#pragma unroll
  for (int off = 32; off; off >>= 1) klp += __shfl_down(klp, off);
  if (lane == 0) redbuf[w] = klp;
  __syncthreads();
  if (t == 0) {
    float s = 0.0f;
#pragma unroll
    for (int i = 0; i < 16; ++i) s += redbuf[i];
    partials[bid] = s;
  }
}

// ---------------- finalize ----------------
__global__ void fin_kernel(const float* __restrict__ partials, float* __restrict__ out) {
  __shared__ double red[256];
  double s = (double)partials[threadIdx.x];
  red[threadIdx.x] = s;
  __syncthreads();
  for (int st = 128; st > 0; st >>= 1) {
    if ((int)threadIdx.x < st) red[threadIdx.x] += red[threadIdx.x + st];
    __syncthreads();
  }
  if (threadIdx.x == 0) out[(size_t)BSZ * DIM] = (float)(red[0] / (double)BSZ);
}

// ---------------- launch ----------------
// ws: [0,16384) float partials[256] (+pad); [16384,+128K) wT_mu; [147456,+128K) wT_sd.
// Total 278528 B.
extern "C" void kernel_launch(void* const* d_in, const int* in_sizes, int n_in,
                              void* d_out, int out_size, void* d_ws, size_t ws_size,
                              hipStream_t stream) {
  const float* z   = (const float*)d_in[0];
  const float* Wmu = (const float*)d_in[1];
  const float* bmu = (const float*)d_in[2];
  const float* Wsd = (const float*)d_in[3];
  const float* bsd = (const float*)d_in[4];
  float* out = (float*)d_out;

  float* partials     = (float*)d_ws;
  unsigned short* wm  = (unsigned short*)((char*)d_ws + 16384);
  unsigned short* wsd = wm + DIM * DIM;

  prep_kernel<<<64, 256, 0, stream>>>(Wmu, Wsd, wm, wsd);
  main_kernel<<<NBLK, NT, 0, stream>>>(z, wm, wsd, bmu, bsd, out, partials);
  fin_kernel<<<1, 256, 0, stream>>>(partials, out);
}

// Round 10
// 56.927 us; speedup vs baseline: 1.7159x; 1.0402x over previous
//
#include <hip/hip_runtime.h>
#include <hip/hip_bf16.h>

#define BSZ  131072
#define DIM  256
#define ROWS 32                    // rows per tile
#define NT   1024                  // 16 waves; wave w owns output cols [w*16, w*16+16)
#define NBLK 256                   // persistent: 1 block/CU
#define TPB  (BSZ / ROWS / NBLK)   // 16 tiles per block

typedef __attribute__((ext_vector_type(8))) short bf16x8;
typedef __attribute__((ext_vector_type(4))) float f32x4;
typedef __attribute__((ext_vector_type(4))) unsigned int u32x4;
typedef __attribute__((ext_vector_type(4))) unsigned short u16x4;

// LDS map (double-buffered both):
//  zbuf[2] : [32 rows][256 bf16 + pad] stride 528  -> 16896 each  @ 0, 16896
//  obuf[2] : [32 rows][256 f32 + pad]  stride 1040 -> 33280 each  @ 33792, 67072
// total 100352
#define ZSTR  528
#define OSTR  1040
#define ZB(b) ((b) * 16896)
#define OB(b) (33792 + (b) * 33280)

__device__ __forceinline__ unsigned short f2bf(float f) {
  unsigned u = __builtin_bit_cast(unsigned, f);
  return (unsigned short)((u + 0x7FFFu + ((u >> 16) & 1u)) >> 16);
}
__device__ __forceinline__ unsigned cvt_pk(float lo, float hi) {
  unsigned r;
  asm("v_cvt_pk_bf16_f32 %0, %1, %2" : "=v"(r) : "v"(lo), "v"(hi));
  return r;
}

// ---------------- prep: f32 W -> bf16 wT, K-major: wT[kb][j][kk] ----------------
__global__ void prep_kernel(const float* __restrict__ Wmu, const float* __restrict__ Wsd,
                            unsigned short* __restrict__ wm, unsigned short* __restrict__ wsd) {
  const int tg = blockIdx.x * 256 + threadIdx.x;   // 16384 threads
  const int j  = tg >> 6, kq = tg & 63;            // row j, k-quad (k0 = kq*4)
  const int dst = ((kq >> 3) << 13) + (j << 5) + ((kq & 7) << 2);
  f32x4 a = *(const f32x4*)(Wmu + j * 256 + kq * 4);
  f32x4 b = *(const f32x4*)(Wsd + j * 256 + kq * 4);
  u16x4 pa, pb;
#pragma unroll
  for (int e = 0; e < 4; ++e) { pa[e] = f2bf(a[e]); pb[e] = f2bf(b[e]); }
  *(u16x4*)(wm + dst)  = pa;
  *(u16x4*)(wsd + dst) = pb;
}

// ---------------- main: persistent, W in regs, ONE barrier per tile ----------------
__global__ __launch_bounds__(NT, 4)
void main_kernel(const float* __restrict__ z,
                 const unsigned short* __restrict__ wm,
                 const unsigned short* __restrict__ wsd,
                 const float* __restrict__ bmu,
                 const float* __restrict__ bsd,
                 float* __restrict__ out,
                 float* __restrict__ partials) {
  __shared__ unsigned char smem[100352];
  __shared__ float redbuf[16];
  const int t = threadIdx.x, lane = t & 63, w = t >> 6;   // w 0..15
  const int bid = blockIdx.x;

  // ---- W fragments, loaded ONCE (wave w -> cols [w*16, w*16+16)) ----
  const int woff = (w * 16 + (lane & 15)) * 32 + (lane >> 4) * 8;
  bf16x8 wfm[8], wfs[8];
#pragma unroll
  for (int kb = 0; kb < 8; ++kb) {
    wfm[kb] = *(const bf16x8*)(wm  + (kb << 13) + woff);
    wfs[kb] = *(const bf16x8*)(wsd + (kb << 13) + woff);
  }
  const int colb = w * 16 + ((lane >> 4) << 2);
  const f32x4 b4m = *(const f32x4*)(bmu + colb);
  const f32x4 b4s = *(const f32x4*)(bsd + colb);

  // ---- per-thread addressing ----
  const int zrow = t >> 5, zc = t & 31;                       // stage: 8 f32 per thread
  const int zwofs = zrow * ZSTR + zc * 16;                    // ds_write_b128 dest
  const int zro   = (lane & 15) * ZSTR + (lane >> 4) * 16;    // + nj*16*ZSTR + kb*64
  const int ow    = (lane & 15) * OSTR + colb * 4;            // + nj*16*OSTR

  const size_t TSTEP = (size_t)NBLK * ROWS * DIM;             // elems between my tiles
  const float* zp = z + (size_t)(bid * ROWS + zrow) * DIM + zc * 8;
  float* op = out + (size_t)(bid * ROWS) * DIM;

  float klp = 0.0f;
  f32x4 pza, pzb;

  // ---- prologue: stage z(0) into buf0; prefetch z(1) into regs ----
  {
    f32x4 a = *(const f32x4*)zp;
    f32x4 b = *(const f32x4*)(zp + 4);
    u32x4 p;
    p[0] = cvt_pk(a[0], a[1]); p[1] = cvt_pk(a[2], a[3]);
    p[2] = cvt_pk(b[0], b[1]); p[3] = cvt_pk(b[2], b[3]);
    *(u32x4*)(smem + ZB(0) + zwofs) = p;
  }
  pza = *(const f32x4*)(zp + TSTEP);
  pzb = *(const f32x4*)(zp + TSTEP + 4);
  asm volatile("s_waitcnt lgkmcnt(0)" ::: "memory");
  __builtin_amdgcn_sched_barrier(0);
  __builtin_amdgcn_s_barrier();

  // ---- tile loop: ONE barrier per tile; stores/stage/compute share one phase ----
#pragma unroll 1
  for (int i = 0; i < TPB; ++i) {
    // A: stage z(i+1) into zbuf[(i+1)&1] (its readers finished at barrier(i-1))
    if (i < TPB - 1) {
      u32x4 p;
      p[0] = cvt_pk(pza[0], pza[1]); p[1] = cvt_pk(pza[2], pza[3]);
      p[2] = cvt_pk(pzb[0], pzb[1]); p[3] = cvt_pk(pzb[2], pzb[3]);
      *(u32x4*)(smem + ZB((i + 1) & 1) + zwofs) = p;
    }
    // B: prefetch z(i+2) (stays in flight across the barrier)
    if (i < TPB - 2) {
      pza = *(const f32x4*)(zp + (size_t)(i + 2) * TSTEP);
      pzb = *(const f32x4*)(zp + (size_t)(i + 2) * TSTEP + 4);
    }

    // C: compute tile i from zbuf[i&1]
    const unsigned char* zb = smem + ZB(i & 1);
    f32x4 am[2], al[2];
    am[0] = (f32x4)0.0f; am[1] = (f32x4)0.0f;
    al[0] = (f32x4)0.0f; al[1] = (f32x4)0.0f;
#pragma unroll
    for (int kb = 0; kb < 8; ++kb)
#pragma unroll
      for (int nj = 0; nj < 2; ++nj) {
        const bf16x8 zf = *(const bf16x8*)(zb + nj * 16 * ZSTR + kb * 64 + zro);
        am[nj] = __builtin_amdgcn_mfma_f32_16x16x32_bf16(wfm[kb], zf, am[nj], 0, 0, 0);
        al[nj] = __builtin_amdgcn_mfma_f32_16x16x32_bf16(wfs[kb], zf, al[nj], 0, 0, 0);
      }

    // D: epilogue -> obuf[i&1] (its readers' data-waits completed before barrier(i-1))
#pragma unroll
    for (int nj = 0; nj < 2; ++nj) {
      f32x4 mu4;
#pragma unroll
      for (int r = 0; r < 4; ++r) {
        float mu = fmaxf(am[nj][r] + b4m[r], 0.0f);
        float ls = fmaxf(al[nj][r] + b4s[r], 0.0f);
        float iv = __expf(-2.0f * ls);
        klp += fmaf(mu * mu, iv, iv) + 2.0f * ls;   // (1+mu^2)*iv + 2*ls; -1 folded at end
        mu4[r] = mu;
      }
      *(f32x4*)(smem + OB(i & 1) + nj * 16 * OSTR + ow) = mu4;
    }

    // E: the single barrier
    asm volatile("s_waitcnt lgkmcnt(0)" ::: "memory");
    __builtin_amdgcn_sched_barrier(0);
    __builtin_amdgcn_s_barrier();

    // F: coalesced NT stores of tile i (wave stores rows 2w, 2w+1; 1KB contiguous each)
#pragma unroll
    for (int rr = 0; rr < 2; ++rr) {
      const int row = w * 2 + rr;
      const f32x4 v = *(const f32x4*)(smem + OB(i & 1) + row * OSTR + lane * 16);
      __builtin_nontemporal_store(v, (f32x4*)(op + (size_t)i * TSTEP + row * DIM + lane * 4));
    }
  }

  // ---- KL reduction ----
  klp = 0.5f * (klp - (float)(TPB * 8));   // 128 elems per lane, each owes -1
#pragma unroll
  for (int off = 32; off; off >>= 1) klp += __shfl_down(klp, off);
  if (lane == 0) redbuf[w] = klp;
  __syncthreads();
  if (t == 0) {
    float s = 0.0f;
#pragma unroll
    for (int i = 0; i < 16; ++i) s += redbuf[i];
    partials[bid] = s;
  }
}

// ---------------- finalize ----------------
__global__ void fin_kernel(const float* __restrict__ partials, float* __restrict__ out) {
  __shared__ double red[256];
  red[threadIdx.x] = (double)partials[threadIdx.x];
  __syncthreads();
  for (int st = 128; st > 0; st >>= 1) {
    if ((int)threadIdx.x < st) red[threadIdx.x] += red[threadIdx.x + st];
    __syncthreads();
  }
  if (threadIdx.x == 0) out[(size_t)BSZ * DIM] = (float)(red[0] / (double)BSZ);
}

// ---------------- launch ----------------
// ws: [0,16384) float partials[256](+pad); [16384,+128K) wT_mu; [147456,+128K) wT_sd.
// Total 278528 B.
extern "C" void kernel_launch(void* const* d_in, const int* in_sizes, int n_in,
                              void* d_out, int out_size, void* d_ws, size_t ws_size,
                              hipStream_t stream) {
  const float* z   = (const float*)d_in[0];
  const float* Wmu = (const float*)d_in[1];
  const float* bmu = (const float*)d_in[2];
  const float* Wsd = (const float*)d_in[3];
  const float* bsd = (const float*)d_in[4];
  float* out = (float*)d_out;

  float* partials     = (float*)d_ws;
  unsigned short* wm  = (unsigned short*)((char*)d_ws + 16384);
  unsigned short* wsd = wm + DIM * DIM;

  prep_kernel<<<64, 256, 0, stream>>>(Wmu, Wsd, wm, wsd);
  main_kernel<<<NBLK, NT, 0, stream>>>(z, wm, wsd, bmu, bsd, out, partials);
  fin_kernel<<<1, 256, 0, stream>>>(partials, out);
}